// Round 1
// baseline (3653.761 us; speedup 1.0000x reference)
//
#include <hip/hip_runtime.h>
#include <hip/hip_bf16.h>

// Fully-fused BetaVAE encoder: one 512-thread block per image.
// All intermediates live in LDS (bf16 storage, fp32 accumulation).
// Weights are read from global with wave-uniform indices -> scalar loads.
//
// LDS map (bytes):
//   [0      , 41616): xs  [6][102][34] bf16 (padded x)   -- later reused:
//        [0    ,25600): h2s [16][50][16] bf16
//        [25600,30720): h3s [32][10][8]  bf16
//   [41616  , 56592): p1s [8][52][18] bf16 (padded pool1 out)
//   [56592  , 60432): p2s [16][12][10] bf16 (padded pool2 out)
//   [60432  , 61456): f   [256] float
#define SMEM_BYTES 61456

__device__ __forceinline__ float b2f(__hip_bfloat16 v) { return __bfloat162float(v); }
__device__ __forceinline__ __hip_bfloat16 f2b(float v) { return __float2bfloat16(v); }

extern "C" __global__ void __launch_bounds__(512, 4)
vae_encoder_kernel(const float* __restrict__ x,
                   const float* __restrict__ w1,  const float* __restrict__ b1,
                   const float* __restrict__ w2,  const float* __restrict__ b2,
                   const float* __restrict__ w3,  const float* __restrict__ b3,
                   const float* __restrict__ wp1, const float* __restrict__ bp1,
                   const float* __restrict__ wp2, const float* __restrict__ bp2,
                   const float* __restrict__ wp3, const float* __restrict__ bp3,
                   const float* __restrict__ wmu, const float* __restrict__ bmu,
                   const float* __restrict__ wlv, const float* __restrict__ blv,
                   float* __restrict__ out)
{
    __shared__ __align__(16) unsigned char smem[SMEM_BYTES];
    __hip_bfloat16* xs  = (__hip_bfloat16*)(smem);            // [6][102][34]
    __hip_bfloat16* h2s = (__hip_bfloat16*)(smem);            // [16][50][16]
    __hip_bfloat16* h3s = (__hip_bfloat16*)(smem + 25600);    // [32][10][8]
    __hip_bfloat16* p1s = (__hip_bfloat16*)(smem + 41616);    // [8][52][18]
    __hip_bfloat16* p2s = (__hip_bfloat16*)(smem + 56592);    // [16][12][10]
    float*          fv  = (float*)(smem + 60432);             // [256]

    const int tid  = threadIdx.x;
    const int b    = blockIdx.x;
    const int lane = tid & 63;
    const int wave = tid >> 6;

    // ---- 0) zero all of LDS (padding borders must be 0) ----
    for (int i = tid; i < SMEM_BYTES / 16; i += 512)
        ((int4*)smem)[i] = int4{0, 0, 0, 0};
    __syncthreads();

    // ---- 1) load x image -> xs (bf16, +1 halo pad all around) ----
    const float* xb = x + (size_t)b * 19200;   // 6*100*32
    for (int i = tid; i < 4800; i += 512) {    // 4800 float4
        float4 v = ((const float4*)xb)[i];
        int c   = i / 800;            // 800 float4 per channel
        int rem = i - c * 800;
        int row = rem >> 3;           // 8 float4 per row of 32
        int c4  = rem & 7;
        int base = c * 3468 + (row + 1) * 34 + (c4 * 4 + 1);
        xs[base + 0] = f2b(v.x); xs[base + 1] = f2b(v.y);
        xs[base + 2] = f2b(v.z); xs[base + 3] = f2b(v.w);
    }
    __syncthreads();

    // ---- 2) stage 1: conv1(3x3 SAME,6->8)+lrelu fused with pool1(2x2/2,8->8) ----
    for (int pos = tid; pos < 800; pos += 512) {   // 50x16 pool positions
        int pr = pos >> 4, pc = pos & 15;
        float acc[8];
        #pragma unroll
        for (int o = 0; o < 8; o++) acc[o] = bp1[o];
        for (int kh = 0; kh < 2; kh++) {
            for (int kw = 0; kw < 2; kw++) {
                // h1 at (y,xc) = (2pr+kh, 2pc+kw); padded window base:
                int yb = 2 * pr + kh;
                int xbase = 2 * pc + kw;
                float h[8];
                #pragma unroll
                for (int o = 0; o < 8; o++) h[o] = b1[o];
                #pragma unroll
                for (int c = 0; c < 6; c++)
                    #pragma unroll
                    for (int dy = 0; dy < 3; dy++)
                        #pragma unroll
                        for (int dx = 0; dx < 3; dx++) {
                            float xv = b2f(xs[c * 3468 + (yb + dy) * 34 + (xbase + dx)]);
                            #pragma unroll
                            for (int o = 0; o < 8; o++)
                                h[o] += w1[((o * 6 + c) * 3 + dy) * 3 + dx] * xv;
                        }
                #pragma unroll
                for (int ic = 0; ic < 8; ic++) {
                    float hv = fmaxf(h[ic], 0.01f * h[ic]);   // leaky_relu
                    #pragma unroll
                    for (int o = 0; o < 8; o++)
                        acc[o] += wp1[((o * 8 + ic) * 2 + kh) * 2 + kw] * hv;
                }
            }
        }
        #pragma unroll
        for (int o = 0; o < 8; o++)
            p1s[o * 936 + (pr + 1) * 18 + (pc + 1)] = f2b(acc[o]);
    }
    __syncthreads();

    // ---- 3) stage 2A: conv2(3x3 SAME,8->16)+lrelu -> h2s (overwrites xs) ----
    for (int pos = tid; pos < 800; pos += 512) {   // 50x16 h2 positions
        int r = pos >> 4, c = pos & 15;
        float h[16];
        #pragma unroll
        for (int o = 0; o < 16; o++) h[o] = b2[o];
        #pragma unroll
        for (int ic = 0; ic < 8; ic++)
            #pragma unroll
            for (int dy = 0; dy < 3; dy++)
                #pragma unroll
                for (int dx = 0; dx < 3; dx++) {
                    float pv = b2f(p1s[ic * 936 + (r + dy) * 18 + (c + dx)]);
                    #pragma unroll
                    for (int o = 0; o < 16; o++)
                        h[o] += w2[((o * 8 + ic) * 3 + dy) * 3 + dx] * pv;
                }
        #pragma unroll
        for (int o = 0; o < 16; o++)
            h2s[o * 800 + pos] = f2b(fmaxf(h[o], 0.01f * h[o]));
    }
    __syncthreads();

    // ---- 4) stage 2B: pool2 (5x2 stride (5,2), 16->16) -> p2s (padded) ----
    {
        int oc0 = __builtin_amdgcn_readfirstlane(wave);   // wave-uniform oc
        for (int sub = 0; sub < 2; sub++) {
            int oc = oc0 + 8 * sub;
            for (int pos = lane; pos < 80; pos += 64) {   // 10x8
                int pr = pos >> 3, pc = pos & 7;
                float a = bp2[oc];
                #pragma unroll
                for (int ic = 0; ic < 16; ic++)
                    #pragma unroll
                    for (int kh = 0; kh < 5; kh++)
                        #pragma unroll
                        for (int kw = 0; kw < 2; kw++)
                            a += wp2[((oc * 16 + ic) * 5 + kh) * 2 + kw] *
                                 b2f(h2s[ic * 800 + (5 * pr + kh) * 16 + (2 * pc + kw)]);
                p2s[oc * 120 + (pr + 1) * 10 + (pc + 1)] = f2b(a);
            }
        }
    }
    __syncthreads();

    // ---- 5) stage 3A: conv3(3x3 SAME,16->32)+lrelu -> h3s ----
    {
        int pos = tid & 127;                                    // 0..127, use <80
        int ocq = __builtin_amdgcn_readfirstlane(tid >> 7);     // 0..3 (8 oc each)
        if (pos < 80) {
            int r = pos >> 3, c = pos & 7;
            float h[8];
            #pragma unroll
            for (int o = 0; o < 8; o++) h[o] = b3[ocq * 8 + o];
            #pragma unroll
            for (int ic = 0; ic < 16; ic++)
                #pragma unroll
                for (int dy = 0; dy < 3; dy++)
                    #pragma unroll
                    for (int dx = 0; dx < 3; dx++) {
                        float pv = b2f(p2s[ic * 120 + (r + dy) * 10 + (c + dx)]);
                        #pragma unroll
                        for (int o = 0; o < 8; o++)
                            h[o] += w3[(((ocq * 8 + o) * 16 + ic) * 3 + dy) * 3 + dx] * pv;
                    }
            #pragma unroll
            for (int o = 0; o < 8; o++)
                h3s[(ocq * 8 + o) * 80 + pos] = f2b(fmaxf(h[o], 0.01f * h[o]));
        }
    }
    __syncthreads();

    // ---- 6) stage 3B: pool3 (5x2 stride (5,2), 32->32) -> f[256] ----
    {
        int oc_g = __builtin_amdgcn_readfirstlane(wave);  // 0..7
        int pos  = lane & 7;                              // 2x4 output grid
        int icg  = lane >> 3;                             // 8 ic-groups of 4
        int pr = pos >> 2, pc = pos & 3;
        for (int sub = 0; sub < 4; sub++) {
            int oc = oc_g * 4 + sub;
            float partial = 0.f;
            #pragma unroll
            for (int j = 0; j < 4; j++) {
                int ic = icg * 4 + j;
                #pragma unroll
                for (int kh = 0; kh < 5; kh++)
                    #pragma unroll
                    for (int kw = 0; kw < 2; kw++)
                        partial += wp3[((oc * 32 + ic) * 5 + kh) * 2 + kw] *
                                   b2f(h3s[ic * 80 + (5 * pr + kh) * 8 + (2 * pc + kw)]);
            }
            partial += __shfl_xor(partial, 8);
            partial += __shfl_xor(partial, 16);
            partial += __shfl_xor(partial, 32);
            if (icg == 0) fv[oc * 8 + pos] = partial + bp3[oc];   // flatten [32][2][4]
        }
    }
    __syncthreads();

    // ---- 7) heads: mu = f@wmu^T + bmu ; lv = clip(f@wlv^T + blv, -5, 0) ----
    {
        int j = wave;          // output row 0..6 (wave 7 idle)
        if (j < 7) {
            #pragma unroll
            for (int head = 0; head < 2; head++) {
                const float* W = head ? wlv : wmu;
                float s = 0.f;
                #pragma unroll
                for (int q = 0; q < 4; q++) {
                    int k = lane + 64 * q;
                    s += fv[k] * W[j * 256 + k];
                }
                #pragma unroll
                for (int m = 1; m < 64; m <<= 1) s += __shfl_xor(s, m);
                if (lane == 0) {
                    float r = s + (head ? blv[j] : bmu[j]);
                    if (head) r = fminf(fmaxf(r, -5.f), 0.f);
                    out[head * 28672 + b * 7 + j] = r;
                }
            }
        }
    }
}

extern "C" void kernel_launch(void* const* d_in, const int* in_sizes, int n_in,
                              void* d_out, int out_size, void* d_ws, size_t ws_size,
                              hipStream_t stream) {
    const float* x   = (const float*)d_in[0];
    const float* w1  = (const float*)d_in[1];
    const float* b1  = (const float*)d_in[2];
    const float* w2  = (const float*)d_in[3];
    const float* b2  = (const float*)d_in[4];
    const float* w3  = (const float*)d_in[5];
    const float* b3  = (const float*)d_in[6];
    const float* wp1 = (const float*)d_in[7];
    const float* bp1 = (const float*)d_in[8];
    const float* wp2 = (const float*)d_in[9];
    const float* bp2 = (const float*)d_in[10];
    const float* wp3 = (const float*)d_in[11];
    const float* bp3 = (const float*)d_in[12];
    const float* wmu = (const float*)d_in[13];
    const float* bmu = (const float*)d_in[14];
    const float* wlv = (const float*)d_in[15];
    const float* blv = (const float*)d_in[16];
    float* out = (float*)d_out;

    hipLaunchKernelGGL(vae_encoder_kernel, dim3(4096), dim3(512), 0, stream,
                       x, w1, b1, w2, b2, w3, b3, wp1, bp1, wp2, bp2, wp3, bp3,
                       wmu, bmu, wlv, blv, out);
}